// Round 1
// baseline (682.445 us; speedup 1.0000x reference)
//
#include <hip/hip_runtime.h>

// QuantisedLinear: out[n,o] = sum_i x[n,i] * w[o,i]
//   w[o,2q]   = (wq[o,q]>>4 & 15) * 2/15 - 1, scaled by scale[o, i/128]
//   w[o,2q+1] = (wq[o,q]    & 15) * 2/15 - 1, scaled likewise
// M=8, N=28672, K=8192. Memory-bound: 470 MB of int32 weight reads.

#define O_TOTAL 28672
#define I_TOTAL 8192
#define QROW    4096      // int32 per weight row
#define NBATCH  8
#define NBLK    64        // scale blocks per row (K/128)
#define CHUNK_I 1024      // x columns staged per chunk
#define CHUNK_Q 512       // int32 per row per chunk
#define NCHUNK  8         // K / CHUNK_I

__global__ __launch_bounds__(256)
void qlinear_kernel(const float* __restrict__ x,
                    const int*   __restrict__ wq,
                    const float* __restrict__ scale,
                    float*       __restrict__ out) {
    __shared__ float xs[NBATCH][CHUNK_I];   // 32 KB

    const int tid  = threadIdx.x;
    const int wave = tid >> 6;
    const int lane = tid & 63;
    const int o0   = blockIdx.x * 32 + wave * 8;   // this wave's 8 output rows

    float acc[64];                                  // [r][n], r=row, n=batch
    #pragma unroll
    for (int i = 0; i < 64; ++i) acc[i] = 0.0f;

    for (int c = 0; c < NCHUNK; ++c) {
        __syncthreads();                            // protect xs from prior chunk readers
        // stage x[:, c*1024 .. c*1024+1023] -> LDS (coalesced float4)
        #pragma unroll
        for (int n = 0; n < NBATCH; ++n) {
            *(float4*)&xs[n][tid * 4] =
                *(const float4*)&x[n * I_TOTAL + c * CHUNK_I + tid * 4];
        }
        __syncthreads();

        #pragma unroll
        for (int j2 = 0; j2 < 8; ++j2) {
            const int q = c * CHUNK_Q + j2 * 64 + lane;   // int32 index in row

            int wraw[8];
            #pragma unroll
            for (int r = 0; r < 8; ++r)
                wraw[r] = wq[(size_t)(o0 + r) * QROW + q];

            // scale block index q/64 == c*8 + j2 : wave-uniform -> scalar loads
            float sc[8];
            #pragma unroll
            for (int r = 0; r < 8; ++r)
                sc[r] = scale[(o0 + r) * NBLK + c * 8 + j2];

            float xv[16];                                  // x[n][2q], x[n][2q+1]
            const int li = j2 * 128 + 2 * lane;
            #pragma unroll
            for (int n = 0; n < 8; ++n) {
                float2 t = *(const float2*)&xs[n][li];
                xv[2 * n]     = t.x;
                xv[2 * n + 1] = t.y;
            }

            #pragma unroll
            for (int r = 0; r < 8; ++r) {
                const float s   = sc[r];
                const float s2  = s * (2.0f / 15.0f);
                const float whi = fmaf((float)((wraw[r] >> 4) & 15), s2, -s);
                const float wlo = fmaf((float)( wraw[r]       & 15), s2, -s);
                #pragma unroll
                for (int n = 0; n < 8; ++n) {
                    acc[r * 8 + n] = fmaf(whi, xv[2 * n],
                                     fmaf(wlo, xv[2 * n + 1], acc[r * 8 + n]));
                }
            }
        }
    }

    // Cross-lane reduction, log2-halving butterfly:
    // after step b, lane L holds sums for values v with v&((2<<b)-1) == L&((2<<b)-1);
    // a[i] maps to v = (i << (b+1)) | (L & ((2<<b)-1)). Final: a[0] = value L.
    float a[64];
    #pragma unroll
    for (int v = 0; v < 64; ++v) a[v] = acc[v];

    #pragma unroll
    for (int b = 0; b < 6; ++b) {
        const int keep = (lane >> b) & 1;
        const int m = 64 >> (b + 1);
        #pragma unroll
        for (int i = 0; i < m; ++i) {
            float lo   = a[2 * i];
            float hi   = a[2 * i + 1];
            float mine = keep ? hi : lo;
            float send = keep ? lo : hi;
            float t    = __shfl_xor(send, 1 << b, 64);
            a[i] = mine + t;
        }
    }

    // value index v == lane: v = r*8 + n
    const int r = lane >> 3;
    const int n = lane & 7;
    out[n * O_TOTAL + (o0 + r)] = a[0];
}

extern "C" void kernel_launch(void* const* d_in, const int* in_sizes, int n_in,
                              void* d_out, int out_size, void* d_ws, size_t ws_size,
                              hipStream_t stream) {
    const float* x     = (const float*)d_in[0];
    const int*   wq    = (const int*)  d_in[1];
    const float* scale = (const float*)d_in[2];
    // d_in[3] (lut) is reproduced arithmetically: lut[b] = (hi*2/15-1, lo*2/15-1)
    float* out = (float*)d_out;

    dim3 grid(O_TOTAL / 32);   // 896 blocks, 32 rows each
    dim3 block(256);
    qlinear_kernel<<<grid, block, 0, stream>>>(x, wq, scale, out);
}

// Round 2
// 645.878 us; speedup vs baseline: 1.0566x; 1.0566x over previous
//
#include <hip/hip_runtime.h>

// QuantisedLinear: out[n,o] = sum_i x[n,i] * w[o,i]
//   wq[o][q] holds one byte b: w[o,2q] = (b>>4)*2/15-1, w[o,2q+1] = (b&15)*2/15-1,
//   both scaled by scale[o, col/128]. Scale folded: w = fma(nib, s*2/15, -s).
// M=8, N=28672, K=8192. Memory-bound: 470 MB int32 weight stream, x (256 KB)
// stays L2/L3-hot. No LDS, no barriers: pure register pipeline, weight loads
// prefetched one iteration ahead.

#define O_TOTAL 28672
#define I_TOTAL 8192
#define QROW    4096      // int32 per weight row
#define NBLK    64        // scale blocks per row (K/128)
#define NITER   32        // K sweep: 128 int32 (256 cols) per iter per wave

__global__ __launch_bounds__(256)
void qlinear_kernel(const float* __restrict__ x,
                    const int*   __restrict__ wq,
                    const float* __restrict__ scale,
                    float*       __restrict__ out) {
    const int tid  = threadIdx.x;
    const int wave = tid >> 6;
    const int lane = tid & 63;
    const int o0   = blockIdx.x * 16 + wave * 4;   // 4 rows per wave, 16 per block

    // lane's weight slice: q = 2*lane + 128*j  (int2 loads, 512 B/wave/row)
    const int* wbase = wq + (size_t)o0 * QROW + 2 * lane;
    const int  half  = lane >> 5;                  // scale-block offset within iter

    float acc[32];                                 // [r][n] flat: r*8+n
    #pragma unroll
    for (int i = 0; i < 32; ++i) acc[i] = 0.0f;

    // prefetch j=0 weights
    int2 wcur[4];
    #pragma unroll
    for (int r = 0; r < 4; ++r)
        wcur[r] = *(const int2*)(wbase + r * QROW);

    for (int j = 0; j < NITER; ++j) {
        // prefetch next iteration's weights (wraps to j=0 on last: harmless, cached)
        const int jn = (j + 1) & (NITER - 1);
        int2 wnxt[4];
        #pragma unroll
        for (int r = 0; r < 4; ++r)
            wnxt[r] = *(const int2*)(wbase + r * QROW + 128 * jn);

        // x columns c0..c0+3 for this lane (L2-resident, 1 KB/wave coalesced)
        const int c0 = 256 * j + 4 * lane;
        float4 xv[8];
        #pragma unroll
        for (int n = 0; n < 8; ++n)
            xv[n] = *(const float4*)(x + n * I_TOTAL + c0);

        // scale block: col/128 = 2j + (lane>>5); all 4 lane cols in same block
        const int b = 2 * j + half;
        float sc[4];
        #pragma unroll
        for (int r = 0; r < 4; ++r)
            sc[r] = scale[(o0 + r) * NBLK + b];

        #pragma unroll
        for (int r = 0; r < 4; ++r) {
            const float s   = sc[r];
            const float s2  = s * (2.0f / 15.0f);
            const int   w01 = wcur[r].x;
            const int   w23 = wcur[r].y;
            const float wA  = fmaf((float)((w01 >> 4) & 15), s2, -s);  // col c0+0
            const float wB  = fmaf((float)( w01       & 15), s2, -s);  // col c0+1
            const float wC  = fmaf((float)((w23 >> 4) & 15), s2, -s);  // col c0+2
            const float wD  = fmaf((float)( w23       & 15), s2, -s);  // col c0+3
            #pragma unroll
            for (int n = 0; n < 8; ++n) {
                float t = fmaf(wA, xv[n].x, acc[r * 8 + n]);
                t       = fmaf(wB, xv[n].y, t);
                t       = fmaf(wC, xv[n].z, t);
                acc[r * 8 + n] = fmaf(wD, xv[n].w, t);
            }
        }

        #pragma unroll
        for (int r = 0; r < 4; ++r) wcur[r] = wnxt[r];
    }

    // In-place butterfly: 32 values x 64 lanes. After 5 halving steps lane L
    // holds value (L&31) summed over its 32-lane half; one xor-32 add completes.
    #pragma unroll
    for (int bs = 0; bs < 5; ++bs) {
        const int keep = (lane >> bs) & 1;
        const int m = 32 >> (bs + 1);
        #pragma unroll
        for (int i = 0; i < m; ++i) {
            float lo   = acc[2 * i];
            float hi   = acc[2 * i + 1];
            float mine = keep ? hi : lo;
            float send = keep ? lo : hi;
            acc[i] = mine + __shfl_xor(send, 1 << bs, 64);
        }
    }
    float v = acc[0] + __shfl_xor(acc[0], 32, 64);

    if (lane < 32) {
        const int r = lane >> 3;   // value index = r*8+n = lane&31
        const int n = lane & 7;
        out[n * O_TOTAL + o0 + r] = v;
    }
}

extern "C" void kernel_launch(void* const* d_in, const int* in_sizes, int n_in,
                              void* d_out, int out_size, void* d_ws, size_t ws_size,
                              hipStream_t stream) {
    const float* x     = (const float*)d_in[0];
    const int*   wq    = (const int*)  d_in[1];
    const float* scale = (const float*)d_in[2];
    // d_in[3] (lut) reproduced arithmetically: lut[b] = ((b>>4)*2/15-1, (b&15)*2/15-1)
    float* out = (float*)d_out;

    dim3 grid(O_TOTAL / 16);   // 1792 blocks x 16 rows
    dim3 block(256);
    qlinear_kernel<<<grid, block, 0, stream>>>(x, wq, scale, out);
}